// Round 2
// baseline (541.714 us; speedup 1.0000x reference)
//
#include <hip/hip_runtime.h>
#include <math.h>

#define NN 20000
#define NE 320000
#define NF (NN*64)

typedef short sh8_t  __attribute__((ext_vector_type(8)));
typedef float fl4_t  __attribute__((ext_vector_type(4)));

__device__ __forceinline__ float silu_f(float x){ return x / (1.0f + expf(-x)); }

// fp32 -> bf16 (RNE) as raw short
__device__ __forceinline__ short f2bf(float f){
  unsigned u = __builtin_bit_cast(unsigned, f);
  unsigned r = (u + 0x7fffu + ((u >> 16) & 1u)) >> 16;
  return (short)r;
}
__device__ __forceinline__ float bf2f(short s){
  unsigned u = ((unsigned)(unsigned short)s) << 16;
  return __builtin_bit_cast(float, u);
}

// ---- Build fragment-ordered bf16 stream for mlp_w2 ----------------------
// Stream layout: frag=(k2*20 + p) p=j*4+T ; [frag][lane][8] ; element j' of
// lane = w2[k2*32+(lane>>4)*8+j'][j*64+T*16+(lane&15)]
__global__ __launch_bounds__(256) void k_prep_w2(
    const float* __restrict__ w2, short* __restrict__ w2f)
{
  int i = blockIdx.x*256 + threadIdx.x;     // 0..20479
  int jp   = i & 7;
  int lane = (i >> 3) & 63;
  int frag = i >> 9;                        // 0..39
  int k2 = frag / 20, p = frag % 20;
  int j = p >> 2, T = p & 3;
  int k = k2*32 + (lane >> 4)*8 + jp;
  int n = j*64 + T*16 + (lane & 15);
  w2f[i] = f2bf(w2[k*320 + n]);
}

// Transpose per-species residual weights (g-major -> f-major).
__global__ __launch_bounds__(256) void k_transpose_res(
    const float* __restrict__ Ws, const float* __restrict__ Wv,
    float* __restrict__ Wst, float* __restrict__ Wvt)
{
  int i = blockIdx.x*256 + threadIdx.x;   // 0..40959
  int spec = i >> 12;
  int g = (i >> 6) & 63;
  int f = i & 63;
  Wst[spec*4096 + f*64 + g] = Ws[i];
  Wvt[spec*4096 + f*64 + g] = Wv[i];
}

// ---- Node pre-pass: h = feats @ W_in / 8. 8 nodes per wave. --------------
__global__ __launch_bounds__(256) void k_node_pre(
    const float* __restrict__ node_feats, const float* __restrict__ W_in_s,
    const float* __restrict__ W_in_v, float* __restrict__ h_s, float* __restrict__ h_v)
{
  __shared__ float4 sh[4][8][64];   // 32 KB
  int wave = threadIdx.x >> 6, lane = threadIdx.x & 63;
  int n0 = blockIdx.x*32 + wave*8;
  #pragma unroll
  for(int nd=0; nd<8; ++nd)
    sh[wave][nd][lane] = *(const float4*)(node_feats + ((size_t)(n0+nd)*64 + lane)*4);
  float as[8], av0[8], av1[8], av2[8];
  #pragma unroll
  for(int nd=0; nd<8; ++nd){ as[nd]=0.f; av0[nd]=0.f; av1[nd]=0.f; av2[nd]=0.f; }
  for(int f=0; f<64; ++f){
    float ws = W_in_s[f*64+lane], wv = W_in_v[f*64+lane];
    #pragma unroll
    for(int nd=0; nd<8; ++nd){
      float4 t = sh[wave][nd][f];
      as[nd]  += t.x*ws;
      av0[nd] += t.y*wv;
      av1[nd] += t.z*wv;
      av2[nd] += t.w*wv;
    }
  }
  #pragma unroll
  for(int nd=0; nd<8; ++nd){
    int o = (n0+nd)*64 + lane;
    h_s[o]      = as[nd] *0.125f;
    h_v[o]      = av0[nd]*0.125f;
    h_v[NF+o]   = av1[nd]*0.125f;
    h_v[2*NF+o] = av2[nd]*0.125f;
  }
}

// ---- Edge kernel: MFMA MLP + message build + scatter ---------------------
// Block = 4 waves, 64 edges; wave owns 16 edges, no __syncthreads needed.
__global__ __launch_bounds__(256) void k_edge(
    const float* __restrict__ vectors, const float* __restrict__ radial,
    const int* __restrict__ senders, const int* __restrict__ receivers,
    const float* __restrict__ mlp_w1, const short* __restrict__ w2f,
    const float* __restrict__ h_s, const float* __restrict__ h_v,
    float* __restrict__ agg_s, float* __restrict__ agg_v)
{
  __shared__ float hid[4][16][68];   // padded: A-frag reads ~2-4 way conflicts only
  __shared__ float ey[4][16][3];
  __shared__ int   esr[4][16][2];
  __shared__ float rad[4][128];
  int wave = threadIdx.x >> 6, lane = threadIdx.x & 63;
  int e0 = blockIdx.x*64 + wave*16;

  rad[wave][lane]    = radial[e0*8 + lane];
  rad[wave][64+lane] = radial[e0*8 + 64 + lane];
  if(lane < 16){
    int e = e0 + lane;
    float vx = vectors[3*e], vy = vectors[3*e+1], vz = vectors[3*e+2];
    float rinv = 1.0f/sqrtf(vx*vx + vy*vy + vz*vz + 1e-12f);
    ey[wave][lane][0]=vx*rinv; ey[wave][lane][1]=vy*rinv; ey[wave][lane][2]=vz*rinv;
    esr[wave][lane][0]=senders[e]; esr[wave][lane][1]=receivers[e];
  }
  // hidden = silu(rad @ w1), lane = hidden unit
  float w1r[8];
  #pragma unroll
  for(int r=0; r<8; ++r) w1r[r] = mlp_w1[r*64+lane];
  #pragma unroll
  for(int t=0; t<16; ++t){
    float acc = 0.f;
    #pragma unroll
    for(int r=0; r<8; ++r) acc += rad[wave][t*8+r]*w1r[r];
    hid[wave][t][lane] = silu_f(acc);
  }

  // w[e][n] = hidden[e][:] @ w2 via MFMA 16x16x32 bf16, A split hi/lo.
  fl4_t C[20];
  #pragma unroll
  for(int p=0; p<20; ++p) C[p] = (fl4_t){0.f,0.f,0.f,0.f};
  int l15 = lane & 15, q = lane >> 4;
  #pragma unroll
  for(int k2=0; k2<2; ++k2){
    const float* hp = &hid[wave][l15][k2*32 + q*8];
    float a[8];
    #pragma unroll
    for(int i=0; i<8; ++i) a[i] = hp[i];
    sh8_t ahi, alo;
    #pragma unroll
    for(int i=0; i<8; ++i){
      short h = f2bf(a[i]);
      ahi[i] = h;
      alo[i] = f2bf(a[i] - bf2f(h));
    }
    const short* bbase = w2f + (size_t)(k2*20)*512 + lane*8;
    #pragma unroll
    for(int p=0; p<20; ++p){
      sh8_t b = *(const sh8_t*)(bbase + p*512);
      C[p] = __builtin_amdgcn_mfma_f32_16x16x32_bf16(ahi, b, C[p], 0, 0, 0);
      C[p] = __builtin_amdgcn_mfma_f32_16x16x32_bf16(alo, b, C[p], 0, 0, 0);
    }
  }

  // Epilogue in C layout: lane owns rows r=q*4+reg (edges), col c=T*16+l15.
  #pragma unroll
  for(int reg=0; reg<4; ++reg){
    int r = q*4 + reg;
    float y0 = ey[wave][r][0], y1 = ey[wave][r][1], y2 = ey[wave][r][2];
    int snd = esr[wave][r][0], rcv = esr[wave][r][1];
    #pragma unroll
    for(int T=0; T<4; ++T){
      int c = T*16 + l15;
      int so = snd*64 + c, ro = rcv*64 + c;
      float ss  = h_s[so];
      float sv0 = h_v[so], sv1 = h_v[NF+so], sv2 = h_v[2*NF+so];
      float dot = sv0*y0 + sv1*y1 + sv2*y2;
      float w0 = C[T][reg], w1v = C[4+T][reg], w2v = C[8+T][reg];
      float w3v = C[12+T][reg], w4v = C[16+T][reg];
      float ms  = w0*ss + w1v*dot;
      float w2s = w2v*ss;
      float mv0 = w2s*y0 + w3v*sv0 + w4v*(sv1*y2 - sv2*y1);
      float mv1 = w2s*y1 + w3v*sv1 + w4v*(sv2*y0 - sv0*y2);
      float mv2 = w2s*y2 + w3v*sv2 + w4v*(sv0*y1 - sv1*y0);
      atomicAdd(&agg_s[ro],      ms);
      atomicAdd(&agg_v[ro],      mv0);
      atomicAdd(&agg_v[NF+ro],   mv1);
      atomicAdd(&agg_v[2*NF+ro], mv2);
    }
  }
}

// ---- Node post-pass: 8 nodes per wave, one reusable LDS buffer. ----------
__global__ __launch_bounds__(256) void k_node_post(
  const float* __restrict__ node_feats, const int* __restrict__ specie,
  const float* __restrict__ agg_s, const float* __restrict__ agg_v,
  const float* __restrict__ Wrst, const float* __restrict__ Wrvt,
  const float* __restrict__ W_out_s, const float* __restrict__ W_out_v,
  const float* __restrict__ W_prod_s, const float* __restrict__ W_prod_v,
  const float* __restrict__ W_lin_s, const float* __restrict__ W_lin_v,
  const float* __restrict__ W_read, float* __restrict__ out_node, float* __restrict__ out_feats)
{
  __shared__ float4 buf[4][8][64];   // 32 KB, reused 3x (intra-wave regions)
  int wave = threadIdx.x >> 6, lane = threadIdx.x & 63;
  int n0 = blockIdx.x*32 + wave*8;
  int sp[8];
  #pragma unroll
  for(int nd=0; nd<8; ++nd) sp[nd] = specie[n0+nd];

  // Stage agg (scaled by 1/AVG_NEIGH)
  #pragma unroll
  for(int nd=0; nd<8; ++nd){
    int o = (n0+nd)*64 + lane;
    buf[wave][nd][lane] = make_float4(agg_s[o]*(1.f/16.f), agg_v[o]*(1.f/16.f),
                                      agg_v[NF+o]*(1.f/16.f), agg_v[2*NF+o]*(1.f/16.f));
  }
  float a_s[8], a0[8], a1[8], a2[8];
  #pragma unroll
  for(int nd=0; nd<8; ++nd){ a_s[nd]=0.f; a0[nd]=0.f; a1[nd]=0.f; a2[nd]=0.f; }
  for(int f=0; f<64; ++f){
    float wos = W_out_s[f*64+lane], wov = W_out_v[f*64+lane];
    #pragma unroll
    for(int nd=0; nd<8; ++nd){
      float4 t = buf[wave][nd][f];
      a_s[nd] += t.x*wos; a0[nd] += t.y*wov; a1[nd] += t.z*wov; a2[nd] += t.w*wov;
    }
  }
  #pragma unroll
  for(int nd=0; nd<8; ++nd){ a_s[nd]*=0.125f; a0[nd]*=0.125f; a1[nd]*=0.125f; a2[nd]*=0.125f; }

  // Stage node_feats, residual matvec (per-species transposed weights)
  #pragma unroll
  for(int nd=0; nd<8; ++nd)
    buf[wave][nd][lane] = *(const float4*)(node_feats + ((size_t)(n0+nd)*64 + lane)*4);
  float r_s[8], r0[8], r1[8], r2[8];
  #pragma unroll
  for(int nd=0; nd<8; ++nd){ r_s[nd]=0.f; r0[nd]=0.f; r1[nd]=0.f; r2[nd]=0.f; }
  for(int f=0; f<64; ++f){
    #pragma unroll
    for(int nd=0; nd<8; ++nd){
      float wrs = Wrst[sp[nd]*4096 + f*64 + lane];
      float wrv = Wrvt[sp[nd]*4096 + f*64 + lane];
      float4 t = buf[wave][nd][f];
      r_s[nd] += t.x*wrs; r0[nd] += t.y*wrv; r1[nd] += t.z*wrv; r2[nd] += t.w*wrv;
    }
  }
  #pragma unroll
  for(int nd=0; nd<8; ++nd){ r_s[nd]*=0.125f; r0[nd]*=0.125f; r1[nd]*=0.125f; r2[nd]*=0.125f; }

  // Polynomial products, stage p into buf
  #pragma unroll
  for(int nd=0; nd<8; ++nd){
    float vv = a0[nd]*a0[nd] + a1[nd]*a1[nd] + a2[nd]*a2[nd];
    float as2 = a_s[nd]*a_s[nd];
    const float* Wp = W_prod_s + sp[nd]*320;
    float p_s = Wp[lane]*a_s[nd] + Wp[64+lane]*as2 + Wp[128+lane]*as2*a_s[nd]
              + Wp[192+lane]*vv + Wp[256+lane]*a_s[nd]*vv;
    const float* Wq = W_prod_v + sp[nd]*256;
    float coef = Wq[lane] + Wq[64+lane]*a_s[nd] + Wq[128+lane]*as2 + Wq[192+lane]*vv;
    buf[wave][nd][lane] = make_float4(p_s, coef*a0[nd], coef*a1[nd], coef*a2[nd]);
  }
  float fs[8], f0[8], f1[8], f2[8];
  #pragma unroll
  for(int nd=0; nd<8; ++nd){ fs[nd]=0.f; f0[nd]=0.f; f1[nd]=0.f; f2[nd]=0.f; }
  for(int f=0; f<64; ++f){
    float wls = W_lin_s[f*64+lane], wlv = W_lin_v[f*64+lane];
    #pragma unroll
    for(int nd=0; nd<8; ++nd){
      float4 t = buf[wave][nd][f];
      fs[nd] += t.x*wls; f0[nd] += t.y*wlv; f1[nd] += t.z*wlv; f2[nd] += t.w*wlv;
    }
  }
  float wr = W_read[lane];
  #pragma unroll
  for(int nd=0; nd<8; ++nd){
    float vs = fs[nd]*0.125f + r_s[nd];
    float v0 = f0[nd]*0.125f + r0[nd];
    float v1 = f1[nd]*0.125f + r1[nd];
    float v2 = f2[nd]*0.125f + r2[nd];
    int o = (n0+nd)*64 + lane;
    float4 o4; o4.x=vs; o4.y=v0; o4.z=v1; o4.w=v2;
    *(float4*)(out_feats + (size_t)o*4) = o4;
    float x = vs * wr;
    #pragma unroll
    for(int off=32; off; off>>=1) x += __shfl_down(x, off);
    if(lane==0) out_node[n0+nd] = x*0.125f;
  }
}

extern "C" void kernel_launch(void* const* d_in, const int* in_sizes, int n_in,
                              void* d_out, int out_size, void* d_ws, size_t ws_size,
                              hipStream_t stream) {
  const float* vectors    = (const float*)d_in[0];
  const float* node_feats = (const float*)d_in[1];
  const int*   node_specie= (const int*)  d_in[2];
  const float* radial     = (const float*)d_in[3];
  const int*   senders    = (const int*)  d_in[4];
  const int*   receivers  = (const int*)  d_in[5];
  const float* W_res_s    = (const float*)d_in[6];
  const float* W_res_v    = (const float*)d_in[7];
  const float* W_in_s     = (const float*)d_in[8];
  const float* W_in_v     = (const float*)d_in[9];
  const float* mlp_w1     = (const float*)d_in[10];
  const float* mlp_w2     = (const float*)d_in[11];
  const float* W_out_s    = (const float*)d_in[12];
  const float* W_out_v    = (const float*)d_in[13];
  const float* W_prod_s   = (const float*)d_in[14];
  const float* W_prod_v   = (const float*)d_in[15];
  const float* W_lin_s    = (const float*)d_in[16];
  const float* W_lin_v    = (const float*)d_in[17];
  const float* W_read     = (const float*)d_in[18];

  float* ws   = (float*)d_ws;
  float* h_s  = ws;                         // NF
  float* h_v  = ws + NF;                    // 3*NF
  float* agg_s= ws + 4*(size_t)NF;          // NF
  float* agg_v= ws + 5*(size_t)NF;          // 3*NF
  float* Wrst = ws + 8*(size_t)NF;          // 40960
  float* Wrvt = ws + 8*(size_t)NF + 40960;  // 40960
  short* w2f  = (short*)(ws + 8*(size_t)NF + 81920);  // 20480 shorts

  hipMemsetAsync(agg_s, 0, (size_t)4*NF*sizeof(float), stream);
  k_prep_w2<<<80, 256, 0, stream>>>(mlp_w2, w2f);
  k_transpose_res<<<160, 256, 0, stream>>>(W_res_s, W_res_v, Wrst, Wrvt);
  k_node_pre<<<625, 256, 0, stream>>>(node_feats, W_in_s, W_in_v, h_s, h_v);
  k_edge<<<NE/64, 256, 0, stream>>>(vectors, radial, senders, receivers,
                                    mlp_w1, w2f, h_s, h_v, agg_s, agg_v);
  k_node_post<<<625, 256, 0, stream>>>(node_feats, node_specie, agg_s, agg_v,
                                       Wrst, Wrvt, W_out_s, W_out_v,
                                       W_prod_s, W_prod_v, W_lin_s, W_lin_v,
                                       W_read, (float*)d_out, (float*)d_out + NN);
}